// Round 1
// baseline (284.085 us; speedup 1.0000x reference)
//
#include <hip/hip_runtime.h>
#include <math.h>

// GNN_2826088481036: 4-layer GCN on B=1e6 independent 3-node graphs, H=32.
//
// Key algebraic fact: A_NORM = ones(3,3)/3, so each GCN layer's aggregation is
// "mean over the 3 nodes, broadcast to all 3 nodes". After layer 1 all node
// features are identical => the whole network collapses to a per-sample MLP:
//   xm   = mean_j x[b,j,:]                      (4)
//   v    = softplus(xm @ W1 + b1)               (32)
//   v    = softplus(v @ Wk + bk), k=2..4        (32)
//   out  = v * (linW[0]+linW[1]+linW[2]) + linb (32)
// 3200 MACs/sample. fp32-exact (threshold is 1.8e-2; we'll be ~1e-6).

#define HC  32
#define BLK 256

__device__ __forceinline__ float softplus_f(float a) {
    // log(1+e^a) = max(a,0) + log(1 + e^-|a|); fast exp/log are plenty accurate
    float t = __expf(-fabsf(a));
    return fmaxf(a, 0.0f) + __logf(1.0f + t);
}

__device__ __forceinline__ void layer32(float (&v)[HC],
                                        const float* __restrict__ W,
                                        const float* __restrict__ bias) {
    float acc[HC];
    #pragma unroll
    for (int f = 0; f < HC; ++f) acc[f] = bias[f];        // uniform -> s_load
    #pragma unroll 8
    for (int g = 0; g < HC; ++g) {
        const float vg = v[g];
        const float* wr = W + g * HC;                     // uniform row
        #pragma unroll
        for (int f = 0; f < HC; ++f)
            acc[f] = fmaf(vg, wr[f], acc[f]);             // v_fmac, SGPR weight
    }
    #pragma unroll
    for (int f = 0; f < HC; ++f) v[f] = softplus_f(acc[f]);
}

__global__ __launch_bounds__(BLK, 3) void gnn_fused(
    const float* __restrict__ x,
    const float* __restrict__ W1, const float* __restrict__ b1,
    const float* __restrict__ W2, const float* __restrict__ b2,
    const float* __restrict__ W3, const float* __restrict__ b3,
    const float* __restrict__ W4, const float* __restrict__ b4,
    const float* __restrict__ linW, const float* __restrict__ linb,
    float* __restrict__ out, int nB)
{
    // stride HC+1 = 33: store bank = (t+f)%32, read bank = 2-way -> conflict-free
    __shared__ float sbuf[BLK * (HC + 1)];

    const int  t    = threadIdx.x;
    const long base = (long)blockIdx.x * BLK;
    const long b    = base + t;
    const bool active = (b < (long)nB);

    // ---- input: 3 aligned float4 loads (x[b,3,4] = 48B, 16B-aligned) ----
    float xm[4] = {0.f, 0.f, 0.f, 0.f};
    if (active) {
        const float4* xp = (const float4*)(x + b * 12);
        float4 n0 = xp[0], n1 = xp[1], n2 = xp[2];
        const float inv3 = 1.0f / 3.0f;
        xm[0] = (n0.x + n1.x + n2.x) * inv3;
        xm[1] = (n0.y + n1.y + n2.y) * inv3;
        xm[2] = (n0.z + n1.z + n2.z) * inv3;
        xm[3] = (n0.w + n1.w + n2.w) * inv3;
    }

    // ---- layer 1: K=4 ----
    float v[HC];
    #pragma unroll
    for (int f = 0; f < HC; ++f) {
        float a = b1[f];
        a = fmaf(xm[0], W1[0 * HC + f], a);
        a = fmaf(xm[1], W1[1 * HC + f], a);
        a = fmaf(xm[2], W1[2 * HC + f], a);
        a = fmaf(xm[3], W1[3 * HC + f], a);
        v[f] = softplus_f(a);
    }

    // ---- layers 2-4: K=32 ----
    layer32(v, W2, b2);
    layer32(v, W3, b3);
    layer32(v, W4, b4);

    // ---- epilogue: out[b,f] = v[f]*sum(linW) + linb ----
    const float s  = linW[0] + linW[1] + linW[2];
    const float lb = linb[0];

    #pragma unroll
    for (int f = 0; f < HC; ++f)
        sbuf[t * (HC + 1) + f] = fmaf(s, v[f], lb);
    __syncthreads();

    // cooperative coalesced float4 store of this block's [BLK x 32] region
    float4* outv = (float4*)out;
    const long base4  = base * (HC / 4);
    const long limit4 = (long)nB * (HC / 4);
    #pragma unroll
    for (int k = 0; k < (HC / 4); ++k) {
        int  i  = t + k * BLK;          // 0..2047 float4 within block
        long g4 = base4 + i;
        if (g4 < limit4) {
            int srow = i >> 3;           // sample row in block
            int fc   = (i & 7) << 2;     // feature start
            const float* p = sbuf + srow * (HC + 1) + fc;
            outv[g4] = make_float4(p[0], p[1], p[2], p[3]);
        }
    }
}

extern "C" void kernel_launch(void* const* d_in, const int* in_sizes, int n_in,
                              void* d_out, int out_size, void* d_ws, size_t ws_size,
                              hipStream_t stream) {
    const float* x    = (const float*)d_in[0];
    const float* W1   = (const float*)d_in[1];
    const float* b1   = (const float*)d_in[2];
    const float* W2   = (const float*)d_in[3];
    const float* b2   = (const float*)d_in[4];
    const float* W3   = (const float*)d_in[5];
    const float* b3   = (const float*)d_in[6];
    const float* W4   = (const float*)d_in[7];
    const float* b4   = (const float*)d_in[8];
    const float* linW = (const float*)d_in[9];
    const float* linb = (const float*)d_in[10];
    float* out = (float*)d_out;

    const int nB   = in_sizes[0] / 12;          // B = 1e6
    const int grid = (nB + BLK - 1) / BLK;
    gnn_fused<<<grid, BLK, 0, stream>>>(x, W1, b1, W2, b2, W3, b3, W4, b4,
                                        linW, linb, out, nB);
}

// Round 2
// 234.348 us; speedup vs baseline: 1.2122x; 1.2122x over previous
//
#include <hip/hip_runtime.h>
#include <math.h>

// GNN_2826088481036 — R2: MFMA version.
// Algebra: A_NORM=ones(3,3)/3 => per-sample MLP (see R1). Layers 2-4 are
// [1M,32]x[32,32] GEMMs -> mfma_f32_16x16x32_bf16 with hi/lo bf16 split of
// both activations and weights (3 products, ~1e-4 abs err).
// Each wave owns 64 samples + a private LDS region [64][36] of packed
// [bf16_hi|bf16_lo] u32 activations -> no __syncthreads needed anywhere.

#define BLK 256
#define ROWSTRIDE 36   // dwords; mult of 4 (16B-aligned rows), 36%32=4 spreads banks

using short8 = __attribute__((ext_vector_type(8))) short;  // 8 bf16 (A/B frag)
using f32x4  = __attribute__((ext_vector_type(4))) float;  // C/D frag

__device__ __forceinline__ short8 as_s8(uint4 u) { return __builtin_bit_cast(short8, u); }

__device__ __forceinline__ float softplus_fast(float a) {
    // ln(1+e^a); a in [-10,10] here, no overflow risk
    return __logf(1.0f + __expf(a));
}

// RNE bf16 hi (as f32 top-16 bits) + truncated bf16 of residual, packed [hi|lo]
__device__ __forceinline__ unsigned pack_hilo(float a) {
    unsigned u  = __float_as_uint(a);
    unsigned hb = (u + 0x7fffu + ((u >> 16) & 1u)) & 0xffff0000u;
    float    r  = a - __uint_as_float(hb);
    unsigned lo = __float_as_uint(r) >> 16;
    return hb | lo;
}

__global__ __launch_bounds__(BLK, 3) void gnn_mfma(
    const float* __restrict__ x,
    const float* __restrict__ W1, const float* __restrict__ b1,
    const float* __restrict__ W2, const float* __restrict__ b2,
    const float* __restrict__ W3, const float* __restrict__ b3,
    const float* __restrict__ W4, const float* __restrict__ b4,
    const float* __restrict__ linW, const float* __restrict__ linb,
    float* __restrict__ out, int nB)
{
    __shared__ unsigned lds[4 * 64 * ROWSTRIDE];   // 36,864 B

    const int tid  = threadIdx.x;
    const int wid  = tid >> 6;
    const int lane = tid & 63;
    const int q    = lane >> 4;    // quad id (k-chunk selector)
    const int l16  = lane & 15;    // row (A) / col (B,C)

    unsigned* myLds = lds + wid * (64 * ROWSTRIDE);
    const int sbase = blockIdx.x * BLK + wid * 64;   // wave's first sample

    // ---------------- phase 0: input mean + layer 1 (K=4, VALU) ----------------
    const int b0 = sbase + lane;
    float xm0 = 0.f, xm1 = 0.f, xm2 = 0.f, xm3 = 0.f;
    if (b0 < nB) {
        const float4* xp = (const float4*)(x + (size_t)b0 * 12);
        float4 n0 = xp[0], n1 = xp[1], n2 = xp[2];
        const float inv3 = 1.0f / 3.0f;
        xm0 = (n0.x + n1.x + n2.x) * inv3;
        xm1 = (n0.y + n1.y + n2.y) * inv3;
        xm2 = (n0.z + n1.z + n2.z) * inv3;
        xm3 = (n0.w + n1.w + n2.w) * inv3;
    }

    {
        unsigned vp[32];
        #pragma unroll
        for (int f = 0; f < 32; ++f) {
            float a = b1[f];                    // uniform -> s_load
            a = fmaf(xm0, W1[f],      a);
            a = fmaf(xm1, W1[32 + f], a);
            a = fmaf(xm2, W1[64 + f], a);
            a = fmaf(xm3, W1[96 + f], a);
            vp[f] = pack_hilo(softplus_fast(a));
        }
        // own row, 8x ds_write_b128 (row base lane*36 dwords = 16B aligned)
        uint4* rowp = (uint4*)(myLds + lane * ROWSTRIDE);
        #pragma unroll
        for (int d = 0; d < 8; ++d)
            rowp[d] = make_uint4(vp[4*d], vp[4*d+1], vp[4*d+2], vp[4*d+3]);
    }

    const float* Ws[3] = { W2, W3, W4 };
    const float* bs[3] = { b2, b3, b4 };
    const float s_lin = linW[0] + linW[1] + linW[2];
    const float lb    = linb[0];

    // ---------------- layers 2..4 via MFMA ----------------
    #pragma unroll
    for (int layer = 0; layer < 3; ++layer) {
        const float* __restrict__ W  = Ws[layer];
        const float* __restrict__ bL = bs[layer];

        // B fragments: B[k][n] = W[k][n]; lane: n = nt*16+l16, k = q*8+j
        uint4 bhi[2], blo[2];
        #pragma unroll
        for (int nt = 0; nt < 2; ++nt) {
            float w[8];
            #pragma unroll
            for (int j = 0; j < 8; ++j)
                w[j] = W[(q * 8 + j) * 32 + nt * 16 + l16];
            #pragma unroll
            for (int d = 0; d < 4; ++d) {
                unsigned u0  = __float_as_uint(w[2*d]);
                unsigned hb0 = (u0 + 0x7fffu + ((u0 >> 16) & 1u)) & 0xffff0000u;
                float    r0  = w[2*d] - __uint_as_float(hb0);
                unsigned lo0 = __float_as_uint(r0) >> 16;
                unsigned u1  = __float_as_uint(w[2*d+1]);
                unsigned hb1 = (u1 + 0x7fffu + ((u1 >> 16) & 1u)) & 0xffff0000u;
                float    r1  = w[2*d+1] - __uint_as_float(hb1);
                unsigned lo1 = __float_as_uint(r1) >> 16;
                (&bhi[nt].x)[d] = hb1 | (hb0 >> 16);        // [h_{2d+1}|h_{2d}]
                (&blo[nt].x)[d] = (lo1 << 16) | lo0;        // [l_{2d+1}|l_{2d}]
            }
        }
        const float bias_v0 = bL[l16];
        const float bias_v1 = bL[16 + l16];

        // A fragments from LDS: lane: m = mt*16+l16, k = q*8+j
        uint4 ahi[4], alo[4];
        #pragma unroll
        for (int mt = 0; mt < 4; ++mt) {
            const uint4* ap = (const uint4*)(myLds + (mt * 16 + l16) * ROWSTRIDE + q * 8);
            uint4 pA = ap[0], pB = ap[1];
            unsigned p[8] = { pA.x, pA.y, pA.z, pA.w, pB.x, pB.y, pB.z, pB.w };
            #pragma unroll
            for (int d = 0; d < 4; ++d) {
                (&ahi[mt].x)[d] = __builtin_amdgcn_perm(p[2*d+1], p[2*d], 0x07060302u);
                (&alo[mt].x)[d] = __builtin_amdgcn_perm(p[2*d+1], p[2*d], 0x05040100u);
            }
        }

        // 24 MFMAs: acc = Ahi*Bhi + Ahi*Blo + Alo*Bhi
        f32x4 acc[4][2];
        #pragma unroll
        for (int mt = 0; mt < 4; ++mt)
            #pragma unroll
            for (int nt = 0; nt < 2; ++nt) {
                f32x4 c = { 0.f, 0.f, 0.f, 0.f };
                c = __builtin_amdgcn_mfma_f32_16x16x32_bf16(as_s8(ahi[mt]), as_s8(bhi[nt]), c, 0, 0, 0);
                c = __builtin_amdgcn_mfma_f32_16x16x32_bf16(as_s8(ahi[mt]), as_s8(blo[nt]), c, 0, 0, 0);
                c = __builtin_amdgcn_mfma_f32_16x16x32_bf16(as_s8(alo[mt]), as_s8(bhi[nt]), c, 0, 0, 0);
                acc[mt][nt] = c;
            }

        // bias + softplus; write back (L2,L3) or final store (L4)
        if (layer < 2) {
            #pragma unroll
            for (int mt = 0; mt < 4; ++mt)
                #pragma unroll
                for (int nt = 0; nt < 2; ++nt)
                    #pragma unroll
                    for (int r = 0; r < 4; ++r) {
                        float a = acc[mt][nt][r] + (nt ? bias_v1 : bias_v0);
                        int srow = mt * 16 + q * 4 + r;               // C: row=quad*4+reg
                        myLds[srow * ROWSTRIDE + nt * 16 + l16] = pack_hilo(softplus_fast(a));
                    }
        } else {
            #pragma unroll
            for (int mt = 0; mt < 4; ++mt)
                #pragma unroll
                for (int nt = 0; nt < 2; ++nt)
                    #pragma unroll
                    for (int r = 0; r < 4; ++r) {
                        float a = acc[mt][nt][r] + (nt ? bias_v1 : bias_v0);
                        float v = softplus_fast(a);
                        int srow = mt * 16 + q * 4 + r;
                        int samp = sbase + srow;
                        if (samp < nB)
                            out[(size_t)samp * 32 + nt * 16 + l16] = fmaf(s_lin, v, lb);
                    }
        }
    }
}

extern "C" void kernel_launch(void* const* d_in, const int* in_sizes, int n_in,
                              void* d_out, int out_size, void* d_ws, size_t ws_size,
                              hipStream_t stream) {
    const float* x    = (const float*)d_in[0];
    const float* W1   = (const float*)d_in[1];
    const float* b1   = (const float*)d_in[2];
    const float* W2   = (const float*)d_in[3];
    const float* b2   = (const float*)d_in[4];
    const float* W3   = (const float*)d_in[5];
    const float* b3   = (const float*)d_in[6];
    const float* W4   = (const float*)d_in[7];
    const float* b4   = (const float*)d_in[8];
    const float* linW = (const float*)d_in[9];
    const float* linb = (const float*)d_in[10];
    float* out = (float*)d_out;

    const int nB   = in_sizes[0] / 12;
    const int grid = (nB + BLK - 1) / BLK;
    gnn_mfma<<<grid, BLK, 0, stream>>>(x, W1, b1, W2, b2, W3, b3, W4, b4,
                                       linW, linb, out, nB);
}

// Round 4
// 198.702 us; speedup vs baseline: 1.4297x; 1.1794x over previous
//
#include <hip/hip_runtime.h>
#include <math.h>

// GNN_2826088481036 — R4 (= R3 with the bf16 pack fixed to plain bit ops;
// __builtin_bit_cast(__hip_bfloat162) doesn't compile on this HIP).
// Per-sample MLP collapse (A_NORM = 1/3 everywhere, see R1/R2).
//  * activations bf16-only (RNE), weights hi/lo split -> 16 MFMA/layer
//  * permuted-K pair layout: LDS dword p of a sample = [feat p+16 | feat p].
//    C-layout gives each lane cols {l16, l16+16} per row -> pack in-lane,
//    zero cross-lane moves; A-frag = one ds_read_b128 per mt tile.
//    Weight B-frags use the same permutation: kappa=2d+e -> feat (q*4+d)+16e.
//  * log2-domain softplus: u = log2(1+2^t); log2e/ln2 cancel through GEMMs.

#define BLK 256
#define RS  20   // LDS row stride (dwords): mult of 4 (16B rows), 20%32 spreads banks

#define LOG2E 1.44269504088896340736f
#define LN2   0.69314718055994530942f

using short8 = __attribute__((ext_vector_type(8))) short;  // 8 bf16 A/B frag
using f32x4  = __attribute__((ext_vector_type(4))) float;  // C/D frag

__device__ __forceinline__ short8 as_s8(uint4 u) { return __builtin_bit_cast(short8, u); }

// RNE bf16 of a float, as low 16 bits (inputs here are never NaN)
__device__ __forceinline__ unsigned bf16_rne(float a) {
    unsigned u = __float_as_uint(a);
    return (u + 0x7fffu + ((u >> 16) & 1u)) >> 16;
}
__device__ __forceinline__ unsigned pack_bf16x2(float lo, float hi) {
    return bf16_rne(lo) | (bf16_rne(hi) << 16);
}

// u = log2(1 + 2^t)  ==  log2e * softplus(t/log2e); 3 instr, 2 transcendental
__device__ __forceinline__ float softplus_log2(float t) {
    return __builtin_amdgcn_logf(1.0f + __builtin_amdgcn_exp2f(t));
}

__global__ __launch_bounds__(BLK, 3) void gnn_mfma4(
    const float* __restrict__ x,
    const float* __restrict__ W1, const float* __restrict__ b1,
    const float* __restrict__ W2, const float* __restrict__ b2,
    const float* __restrict__ W3, const float* __restrict__ b3,
    const float* __restrict__ W4, const float* __restrict__ b4,
    const float* __restrict__ linW, const float* __restrict__ linb,
    float* __restrict__ out, int nB)
{
    __shared__ unsigned lds[4 * 64 * RS];          // 20,480 B

    const int tid  = threadIdx.x;
    const int wid  = tid >> 6;
    const int lane = tid & 63;
    const int q    = lane >> 4;    // k-chunk selector (A/B), row-quad (C)
    const int l16  = lane & 15;    // row (A) / col (B,C)

    unsigned* myLds = lds + wid * (64 * RS);
    const int sbase = blockIdx.x * BLK + wid * 64;

    // ---------------- layer 1 (K=4, VALU, t-domain) ----------------
    const int b0 = sbase + lane;
    float xm0 = 0.f, xm1 = 0.f, xm2 = 0.f, xm3 = 0.f;
    if (b0 < nB) {
        const float4* xp = (const float4*)(x + (size_t)b0 * 12);
        float4 n0 = xp[0], n1 = xp[1], n2 = xp[2];
        const float k = LOG2E / 3.0f;              // fold mean and log2e
        xm0 = (n0.x + n1.x + n2.x) * k;
        xm1 = (n0.y + n1.y + n2.y) * k;
        xm2 = (n0.z + n1.z + n2.z) * k;
        xm3 = (n0.w + n1.w + n2.w) * k;
    }
    {
        float u[32];
        #pragma unroll
        for (int f = 0; f < 32; ++f) {
            float t = LOG2E * b1[f];               // uniform -> scalar pipe
            t = fmaf(xm0, W1[f],      t);
            t = fmaf(xm1, W1[32 + f], t);
            t = fmaf(xm2, W1[64 + f], t);
            t = fmaf(xm3, W1[96 + f], t);
            u[f] = softplus_log2(t);
        }
        // own row: pair p = [u[p+16] | u[p]], 16 dwords contiguous -> 4x b128
        uint4* rowp = (uint4*)(myLds + lane * RS);
        #pragma unroll
        for (int d = 0; d < 4; ++d)
            rowp[d] = make_uint4(pack_bf16x2(u[4*d + 0], u[4*d + 16]),
                                 pack_bf16x2(u[4*d + 1], u[4*d + 17]),
                                 pack_bf16x2(u[4*d + 2], u[4*d + 18]),
                                 pack_bf16x2(u[4*d + 3], u[4*d + 19]));
    }

    const float* Ws[3] = { W2, W3, W4 };
    const float* bs[3] = { b2, b3, b4 };
    const float s_lin_ln2 = (linW[0] + linW[1] + linW[2]) * LN2;
    const float lb        = linb[0];

    // ---------------- layers 2..4 via MFMA ----------------
    #pragma unroll
    for (int layer = 0; layer < 3; ++layer) {
        const float* __restrict__ W  = Ws[layer];
        const float* __restrict__ bL = bs[layer];

        // B frags, permuted K: kappa=2d+e (+q*8) -> feature (q*4+d) + 16*e
        uint4 bhi[2], blo[2];
        #pragma unroll
        for (int nt = 0; nt < 2; ++nt) {
            #pragma unroll
            for (int d = 0; d < 4; ++d) {
                float w0 = W[(q * 4 + d) * 32      + nt * 16 + l16];
                float w1 = W[(q * 4 + d + 16) * 32 + nt * 16 + l16];
                unsigned h0 = bf16_rne(w0), h1 = bf16_rne(w1);
                float w0h = __uint_as_float(h0 << 16);
                float w1h = __uint_as_float(h1 << 16);
                (&bhi[nt].x)[d] = h0 | (h1 << 16);
                (&blo[nt].x)[d] = pack_bf16x2(w0 - w0h, w1 - w1h);
            }
        }
        const float bias0 = LOG2E * bL[l16];
        const float bias1 = LOG2E * bL[16 + l16];

        // A frags: one aligned ds_read_b128 per mt (row mt*16+l16, dwords q*4..q*4+3)
        uint4 afr[4];
        #pragma unroll
        for (int mt = 0; mt < 4; ++mt)
            afr[mt] = *(const uint4*)(myLds + (mt * 16 + l16) * RS + q * 4);

        // 16 MFMAs: acc = A*Bhi + A*Blo
        f32x4 acc[4][2];
        #pragma unroll
        for (int mt = 0; mt < 4; ++mt)
            #pragma unroll
            for (int nt = 0; nt < 2; ++nt) {
                f32x4 c = { 0.f, 0.f, 0.f, 0.f };
                c = __builtin_amdgcn_mfma_f32_16x16x32_bf16(as_s8(afr[mt]), as_s8(blo[nt]), c, 0, 0, 0);
                c = __builtin_amdgcn_mfma_f32_16x16x32_bf16(as_s8(afr[mt]), as_s8(bhi[nt]), c, 0, 0, 0);
                acc[mt][nt] = c;
            }

        if (layer < 2) {
            // softplus + pack pair (cols l16 / l16+16) + one ds_write per (mt,r)
            #pragma unroll
            for (int mt = 0; mt < 4; ++mt)
                #pragma unroll
                for (int r = 0; r < 4; ++r) {
                    float v0 = softplus_log2(acc[mt][0][r] + bias0);
                    float v1 = softplus_log2(acc[mt][1][r] + bias1);
                    myLds[(mt * 16 + q * 4 + r) * RS + l16] = pack_bf16x2(v0, v1);
                }
        } else {
            #pragma unroll
            for (int mt = 0; mt < 4; ++mt)
                #pragma unroll
                for (int r = 0; r < 4; ++r) {
                    int samp = sbase + mt * 16 + q * 4 + r;
                    if (samp < nB) {
                        float v0 = softplus_log2(acc[mt][0][r] + bias0);
                        float v1 = softplus_log2(acc[mt][1][r] + bias1);
                        float* op = out + (size_t)samp * 32;
                        op[l16]      = fmaf(s_lin_ln2, v0, lb);
                        op[16 + l16] = fmaf(s_lin_ln2, v1, lb);
                    }
                }
        }
    }
}

extern "C" void kernel_launch(void* const* d_in, const int* in_sizes, int n_in,
                              void* d_out, int out_size, void* d_ws, size_t ws_size,
                              hipStream_t stream) {
    const float* x    = (const float*)d_in[0];
    const float* W1   = (const float*)d_in[1];
    const float* b1   = (const float*)d_in[2];
    const float* W2   = (const float*)d_in[3];
    const float* b2   = (const float*)d_in[4];
    const float* W3   = (const float*)d_in[5];
    const float* b3   = (const float*)d_in[6];
    const float* W4   = (const float*)d_in[7];
    const float* b4   = (const float*)d_in[8];
    const float* linW = (const float*)d_in[9];
    const float* linb = (const float*)d_in[10];
    float* out = (float*)d_out;

    const int nB   = in_sizes[0] / 12;
    const int grid = (nB + BLK - 1) / BLK;
    gnn_mfma4<<<grid, BLK, 0, stream>>>(x, W1, b1, W2, b2, W3, b3, W4, b4,
                                        linW, linb, out, nB);
}